// Round 1
// baseline (225.236 us; speedup 1.0000x reference)
//
#include <hip/hip_runtime.h>
#include <hip/hip_bf16.h>
#include <stdint.h>

typedef __attribute__((ext_vector_type(8))) short short8;
typedef __attribute__((ext_vector_type(4))) float f32x4;
typedef __attribute__((ext_vector_type(4))) unsigned short u16x4;

__device__ __forceinline__ float bf2f(unsigned short u) {
  union { unsigned int u; float f; } x; x.u = ((unsigned int)u) << 16; return x.f;
}
__device__ __forceinline__ unsigned short f2bf(float f) {
  union { float f; unsigned int u; } x; x.f = f;
  unsigned int u = x.u;
  return (unsigned short)((u + 0x7fffu + ((u >> 16) & 1u)) >> 16);
}

__device__ __forceinline__ void gload_lds16(const void* g, void* l) {
  __builtin_amdgcn_global_load_lds(
      (const __attribute__((address_space(1))) void*)g,
      (__attribute__((address_space(3))) void*)l, 16, 0, 0);
}

// ---------------- fp32 -> bf16 converts ----------------
__global__ void cvt4(const float* __restrict__ s, unsigned short* __restrict__ d) {
  int i = (blockIdx.x * 256 + threadIdx.x) * 4;
  f32x4 f = *(const f32x4*)(s + i);
  u16x4 o = { f2bf(f[0]), f2bf(f[1]), f2bf(f[2]), f2bf(f[3]) };
  *(u16x4*)(d + i) = o;
}

__global__ void cvt_w(const float* __restrict__ w0, const float* __restrict__ w1,
                      const float* __restrict__ w2, const float* __restrict__ w3,
                      unsigned short* __restrict__ dst) {
  const float* s = blockIdx.z == 0 ? w0 : blockIdx.z == 1 ? w1 : blockIdx.z == 2 ? w2 : w3;
  unsigned short* d = dst + (size_t)blockIdx.z * 1048576;
  int i = (blockIdx.x * 256 + threadIdx.x) * 4;
  f32x4 f = *(const f32x4*)(s + i);
  u16x4 o = { f2bf(f[0]), f2bf(f[1]), f2bf(f[2]), f2bf(f[3]) };
  *(u16x4*)(d + i) = o;
}

// ---------------- NT bf16 GEMM: C[m][n] = sum_k A[m][k]*W[n][k] + bias[n] ----
// MODE 0: z selects {wq,wk,wv}; writes bf16 to head-major QKV[z][b][h][s][d]
// MODE 1: single weight; writes fp32 row-major (d_out)
template <int MODE>
__global__ __launch_bounds__(256)
void gemm_bt(const unsigned short* __restrict__ A,
             const unsigned short* __restrict__ Wbase,
             const float* __restrict__ b0, const float* __restrict__ b1,
             const float* __restrict__ b2,
             unsigned short* __restrict__ obf, float* __restrict__ of32) {
  const int K = 1024;
  const int z = blockIdx.z;
  const unsigned short* W = Wbase + (size_t)z * 1048576;
  const float* bias = (z == 0) ? b0 : (z == 1) ? b1 : b2;

  const int n0 = blockIdx.x * 128, m0 = blockIdx.y * 128;
  const int tid = threadIdx.x, lane = tid & 63, w = tid >> 6;
  const int wr = w >> 1, wc = w & 1;

  __shared__ unsigned short lA[128 * 32];
  __shared__ unsigned short lB[128 * 32];

  f32x4 acc[4][4] = {};

  const int r = lane & 15, koff = (lane >> 4) * 8;

  for (int k0 = 0; k0 < K; k0 += 32) {
    __syncthreads();
#pragma unroll
    for (int i = 0; i < 2; ++i) {
      int c = i * 256 + tid;
      gload_lds16(A + (size_t)(m0 + (c >> 2)) * K + k0 + (c & 3) * 8, &lA[c * 8]);
      gload_lds16(W + (size_t)(n0 + (c >> 2)) * K + k0 + (c & 3) * 8, &lB[c * 8]);
    }
    __syncthreads();
    short8 af[4], bfr[4];
#pragma unroll
    for (int m = 0; m < 4; ++m)
      af[m] = *(const short8*)&lA[(wr * 64 + m * 16 + r) * 32 + koff];
#pragma unroll
    for (int n = 0; n < 4; ++n)
      bfr[n] = *(const short8*)&lB[(wc * 64 + n * 16 + r) * 32 + koff];
#pragma unroll
    for (int m = 0; m < 4; ++m)
#pragma unroll
      for (int n = 0; n < 4; ++n)
        acc[m][n] = __builtin_amdgcn_mfma_f32_16x16x32_bf16(af[m], bfr[n], acc[m][n], 0, 0, 0);
  }

  const int rb = (lane >> 4) * 4, cl = lane & 15;
#pragma unroll
  for (int m = 0; m < 4; ++m) {
#pragma unroll
    for (int n = 0; n < 4; ++n) {
      int col = n0 + wc * 64 + n * 16 + cl;
      float bias_v = bias[col];
#pragma unroll
      for (int i = 0; i < 4; ++i) {
        int row = m0 + wr * 64 + m * 16 + rb + i;
        float v = acc[m][n][i] + bias_v;
        if (MODE == 0) {
          int bb = row >> 11, s = row & 2047, hh = col >> 6, d = col & 63;
          obf[(((size_t)z * 32 + bb * 16 + hh) * 2048 + s) * 64 + d] = f2bf(v);
        } else {
          of32[(size_t)row * 1024 + col] = v;
        }
      }
    }
  }
}

// ---------------- windowed attention, fp32 vector, online softmax ----------
// grid: (S/64, nH, B), block 256. 4 lanes per query (16 dims each).
__global__ __launch_bounds__(256)
void attn_win(const unsigned short* __restrict__ QKV, unsigned short* __restrict__ AO) {
  const int S = 2048;
  const int b = blockIdx.z, h = blockIdx.y, q0 = blockIdx.x * 64;
  const unsigned short* Qh = QKV + ((size_t)(b * 16 + h)) * S * 64;
  const unsigned short* Kh = Qh + (size_t)4194304;
  const unsigned short* Vh = Qh + (size_t)8388608;

  const int tid = threadIdx.x, lane = tid & 63, w = tid >> 6;
  const int qi = q0 + w * 16 + (lane >> 2);
  const int t = lane & 3;

  __shared__ float Kl[64 * 64];
  __shared__ float Vl[64 * 64];

  float q[16];
  {
    const unsigned short* qp = Qh + (size_t)qi * 64 + t * 16;
    short8 a = *(const short8*)qp;
    short8 c = *(const short8*)(qp + 8);
#pragma unroll
    for (int i = 0; i < 8; ++i) {
      q[i] = bf2f((unsigned short)a[i]) * 0.125f;
      q[8 + i] = bf2f((unsigned short)c[i]) * 0.125f;
    }
  }

  float mrun = -1e30f, lrun = 0.f, acc[16];
#pragma unroll
  for (int d = 0; d < 16; ++d) acc[d] = 0.f;

  int kt0 = q0 - 256; if (kt0 < 0) kt0 = 0;
  for (int kt = kt0; kt <= q0; kt += 64) {
    __syncthreads();
    {
      int row = tid >> 2, col0 = (tid & 3) * 16;
      const unsigned short* kg = Kh + (size_t)(kt + row) * 64 + col0;
      const unsigned short* vg = Vh + (size_t)(kt + row) * 64 + col0;
      short8 ka = *(const short8*)kg, kb = *(const short8*)(kg + 8);
      short8 va = *(const short8*)vg, vb = *(const short8*)(vg + 8);
      float* kd = &Kl[row * 64 + col0];
      float* vd = &Vl[row * 64 + col0];
#pragma unroll
      for (int i = 0; i < 8; ++i) {
        kd[i] = bf2f((unsigned short)ka[i]); kd[8 + i] = bf2f((unsigned short)kb[i]);
        vd[i] = bf2f((unsigned short)va[i]); vd[8 + i] = bf2f((unsigned short)vb[i]);
      }
    }
    __syncthreads();

    const int jhi = qi - kt;          // j <= jhi  (kj <= qi)
    const int jlo = qi - 256 - kt;    // j >= jlo  (kj >= qi-256)
    for (int j = 0; j < 64; ++j) {
      if (j > jhi || j < jlo) continue;
      float s = 0.f;
#pragma unroll
      for (int d4 = 0; d4 < 4; ++d4) {
        f32x4 kv = *(const f32x4*)&Kl[j * 64 + t * 16 + d4 * 4];
        s += q[d4 * 4 + 0] * kv[0] + q[d4 * 4 + 1] * kv[1] +
             q[d4 * 4 + 2] * kv[2] + q[d4 * 4 + 3] * kv[3];
      }
      s += __shfl_xor(s, 1);
      s += __shfl_xor(s, 2);
      if (s > mrun) {
        float sc = __expf(mrun - s);
        lrun *= sc;
#pragma unroll
        for (int d = 0; d < 16; ++d) acc[d] *= sc;
        mrun = s;
      }
      float p = __expf(s - mrun);
      lrun += p;
#pragma unroll
      for (int d4 = 0; d4 < 4; ++d4) {
        f32x4 vv = *(const f32x4*)&Vl[j * 64 + t * 16 + d4 * 4];
        acc[d4 * 4 + 0] += p * vv[0];
        acc[d4 * 4 + 1] += p * vv[1];
        acc[d4 * 4 + 2] += p * vv[2];
        acc[d4 * 4 + 3] += p * vv[3];
      }
    }
  }

  float inv = 1.f / lrun;
  short8 o0, o1;
#pragma unroll
  for (int i = 0; i < 8; ++i) {
    o0[i] = (short)f2bf(acc[i] * inv);
    o1[i] = (short)f2bf(acc[8 + i] * inv);
  }
  unsigned short* op = AO + ((size_t)(b * 2048 + qi)) * 1024 + h * 64 + t * 16;
  *(short8*)op = o0;
  *(short8*)(op + 8) = o1;
}

extern "C" void kernel_launch(void* const* d_in, const int* in_sizes, int n_in,
                              void* d_out, int out_size, void* d_ws, size_t ws_size,
                              hipStream_t stream) {
  const float* X  = (const float*)d_in[0];
  const float* wq = (const float*)d_in[1];
  const float* bq = (const float*)d_in[2];
  const float* wk = (const float*)d_in[3];
  const float* bk = (const float*)d_in[4];
  const float* wv = (const float*)d_in[5];
  const float* bv = (const float*)d_in[6];
  const float* wo = (const float*)d_in[7];
  const float* bo = (const float*)d_in[8];
  float* out = (float*)d_out;

  // workspace layout (ushort elems): Xb[4194304] | Wb[4x1048576] | QKV[3x4194304] | AO[4194304]
  unsigned short* Xb  = (unsigned short*)d_ws;
  unsigned short* Wb  = Xb + 4194304;
  unsigned short* QKV = Wb + 4194304;
  unsigned short* AO  = QKV + 12582912;

  cvt4<<<dim3(4096), dim3(256), 0, stream>>>(X, Xb);
  cvt_w<<<dim3(1024, 1, 4), dim3(256), 0, stream>>>(wq, wk, wv, wo, Wb);
  gemm_bt<0><<<dim3(8, 32, 3), dim3(256), 0, stream>>>(Xb, Wb, bq, bk, bv, QKV, nullptr);
  attn_win<<<dim3(32, 16, 2), dim3(256), 0, stream>>>(QKV, AO);
  gemm_bt<1><<<dim3(8, 32, 1), dim3(256), 0, stream>>>(AO, Wb + 3 * 1048576, bo, bo, bo, nullptr, out);
}

// Round 2
// 115.574 us; speedup vs baseline: 1.9488x; 1.9488x over previous
//
#include <hip/hip_runtime.h>
#include <hip/hip_bf16.h>
#include <stdint.h>

typedef __attribute__((ext_vector_type(8))) short short8;
typedef __attribute__((ext_vector_type(4))) float f32x4;
typedef __attribute__((ext_vector_type(4))) unsigned short u16x4;

__device__ __forceinline__ float bf2f(unsigned short u) {
  union { unsigned int u; float f; } x; x.u = ((unsigned int)u) << 16; return x.f;
}
__device__ __forceinline__ unsigned short f2bf(float f) {
  union { float f; unsigned int u; } x; x.f = f;
  unsigned int u = x.u;
  return (unsigned short)((u + 0x7fffu + ((u >> 16) & 1u)) >> 16);
}

__device__ __forceinline__ void gload_lds16(const void* g, void* l) {
  __builtin_amdgcn_global_load_lds(
      (const __attribute__((address_space(1))) void*)g,
      (__attribute__((address_space(3))) void*)l, 16, 0, 0);
}

// ---------------- fp32 -> bf16 converts ----------------
__global__ void cvt4(const float* __restrict__ s, unsigned short* __restrict__ d) {
  int i = (blockIdx.x * 256 + threadIdx.x) * 4;
  f32x4 f = *(const f32x4*)(s + i);
  u16x4 o = { f2bf(f[0]), f2bf(f[1]), f2bf(f[2]), f2bf(f[3]) };
  *(u16x4*)(d + i) = o;
}

__global__ void cvt_w(const float* __restrict__ w0, const float* __restrict__ w1,
                      const float* __restrict__ w2, const float* __restrict__ w3,
                      unsigned short* __restrict__ dst) {
  const float* s = blockIdx.z == 0 ? w0 : blockIdx.z == 1 ? w1 : blockIdx.z == 2 ? w2 : w3;
  unsigned short* d = dst + (size_t)blockIdx.z * 1048576;
  int i = (blockIdx.x * 256 + threadIdx.x) * 4;
  f32x4 f = *(const f32x4*)(s + i);
  u16x4 o = { f2bf(f[0]), f2bf(f[1]), f2bf(f[2]), f2bf(f[3]) };
  *(u16x4*)(d + i) = o;
}

// ---------------- NT bf16 GEMM: C[m][n] = sum_k A[m][k]*W[n][k] + bias[n] ----
// MODE 0: z selects {wq,wk,wv}; Q,K -> head-major [z][b][h][s][d] bf16;
//         V (z==2) -> TRANSPOSED [b][h][d][s] bf16 (for attention B-frags)
// MODE 1: single weight; writes fp32 row-major (d_out)
template <int MODE>
__global__ __launch_bounds__(256)
void gemm_bt(const unsigned short* __restrict__ A,
             const unsigned short* __restrict__ Wbase,
             const float* __restrict__ b0, const float* __restrict__ b1,
             const float* __restrict__ b2,
             unsigned short* __restrict__ obf, float* __restrict__ of32) {
  const int K = 1024;
  const int z = blockIdx.z;
  const unsigned short* W = Wbase + (size_t)z * 1048576;
  const float* bias = (z == 0) ? b0 : (z == 1) ? b1 : b2;

  const int n0 = blockIdx.x * 128, m0 = blockIdx.y * 128;
  const int tid = threadIdx.x, lane = tid & 63, w = tid >> 6;
  const int wr = w >> 1, wc = w & 1;

  __shared__ unsigned short lA[128 * 32];
  __shared__ unsigned short lB[128 * 32];

  f32x4 acc[4][4] = {};

  const int r = lane & 15, koff = (lane >> 4) * 8;

  for (int k0 = 0; k0 < K; k0 += 32) {
    __syncthreads();
#pragma unroll
    for (int i = 0; i < 2; ++i) {
      int c = i * 256 + tid;
      gload_lds16(A + (size_t)(m0 + (c >> 2)) * K + k0 + (c & 3) * 8, &lA[c * 8]);
      gload_lds16(W + (size_t)(n0 + (c >> 2)) * K + k0 + (c & 3) * 8, &lB[c * 8]);
    }
    __syncthreads();
    short8 af[4], bfr[4];
#pragma unroll
    for (int m = 0; m < 4; ++m)
      af[m] = *(const short8*)&lA[(wr * 64 + m * 16 + r) * 32 + koff];
#pragma unroll
    for (int n = 0; n < 4; ++n)
      bfr[n] = *(const short8*)&lB[(wc * 64 + n * 16 + r) * 32 + koff];
#pragma unroll
    for (int m = 0; m < 4; ++m)
#pragma unroll
      for (int n = 0; n < 4; ++n)
        acc[m][n] = __builtin_amdgcn_mfma_f32_16x16x32_bf16(af[m], bfr[n], acc[m][n], 0, 0, 0);
  }

  const int rb = (lane >> 4) * 4, cl = lane & 15;
#pragma unroll
  for (int m = 0; m < 4; ++m) {
#pragma unroll
    for (int n = 0; n < 4; ++n) {
      int col = n0 + wc * 64 + n * 16 + cl;
      float bias_v = bias[col];
      int row0 = m0 + wr * 64 + m * 16 + rb;
      if (MODE == 0) {
        int hh = col >> 6, d = col & 63;
        int bb = row0 >> 11, s0 = row0 & 2047;
        if (z == 2) {
          u16x4 pk;
#pragma unroll
          for (int i = 0; i < 4; ++i) pk[i] = f2bf(acc[m][n][i] + bias_v);
          *(u16x4*)&obf[(((size_t)(64 + bb * 16 + hh)) * 64 + d) * 2048 + s0] = pk;
        } else {
#pragma unroll
          for (int i = 0; i < 4; ++i)
            obf[(((size_t)(z * 32 + bb * 16 + hh)) * 2048 + s0 + i) * 64 + d] =
                f2bf(acc[m][n][i] + bias_v);
        }
      } else {
#pragma unroll
        for (int i = 0; i < 4; ++i)
          of32[(size_t)(row0 + i) * 1024 + col] = acc[m][n][i] + bias_v;
      }
    }
  }
}

// ---------------- MFMA flash attention, window=256 ----------------
// grid (S/128, nH, B), block 256 = 4 waves. Wave owns 32 query rows.
// S[q][k] tiles via mfma(Q-frag, K-frag); online softmax over 16-lane k dim;
// P -> per-wave XOR-swizzled LDS -> A-frags; PV vs transposed-V global frags.
__global__ __launch_bounds__(256)
void attn_mfma(const unsigned short* __restrict__ QKV, unsigned short* __restrict__ AO) {
  const int S = 2048;
  const int b = blockIdx.z, h = blockIdx.y;
  const int q0 = blockIdx.x * 128;
  const size_t hb = (size_t)(b * 16 + h);
  const unsigned short* Qh = QKV + hb * (S * 64);
  const unsigned short* Kh = QKV + 4194304 + hb * (S * 64);
  const unsigned short* Vt = QKV + 8388608 + hb * (S * 64);  // [64][2048]

  const int tid = threadIdx.x;
  const int lane = tid & 63, w = tid >> 6;
  const int c = lane & 15, g = lane >> 4;
  const int qw0 = q0 + 32 * w;

  __shared__ unsigned short Plds[4][1024];
  char* Pb = (char*)&Plds[w][0];

  // Q fragments: A[q=c][d=32*cs+g*8+e], rows qw0+16*mi+c
  short8 qa[2][2];
#pragma unroll
  for (int mi = 0; mi < 2; ++mi)
#pragma unroll
    for (int cs = 0; cs < 2; ++cs)
      qa[mi][cs] = *(const short8*)(Qh + (size_t)(qw0 + 16 * mi + c) * 64 + 32 * cs + g * 8);

  f32x4 o[2][4] = {};
  float mrow[2][4], lsum[2][4];
#pragma unroll
  for (int mi = 0; mi < 2; ++mi)
#pragma unroll
    for (int r = 0; r < 4; ++r) { mrow[mi][r] = -1e30f; lsum[mi][r] = 0.f; }

  int kt0 = qw0 - 256; if (kt0 < 0) kt0 = 0;
  const int ktlast = qw0;

  short8 kf[2][2], vf[4];
#pragma unroll
  for (int ni = 0; ni < 2; ++ni)
#pragma unroll
    for (int cs = 0; cs < 2; ++cs)
      kf[ni][cs] = *(const short8*)(Kh + (size_t)(kt0 + 16 * ni + c) * 64 + 32 * cs + g * 8);
#pragma unroll
  for (int ni = 0; ni < 4; ++ni)
    vf[ni] = *(const short8*)(Vt + (size_t)(16 * ni + c) * 2048 + kt0 + g * 8);

  for (int kt = kt0; kt <= ktlast; kt += 32) {
    const int ktn = (kt + 32 <= ktlast) ? kt + 32 : kt;
    // prefetch next K/V fragments (register double-buffer)
    short8 kfn[2][2], vfn[4];
#pragma unroll
    for (int ni = 0; ni < 2; ++ni)
#pragma unroll
      for (int cs = 0; cs < 2; ++cs)
        kfn[ni][cs] = *(const short8*)(Kh + (size_t)(ktn + 16 * ni + c) * 64 + 32 * cs + g * 8);
#pragma unroll
    for (int ni = 0; ni < 4; ++ni)
      vfn[ni] = *(const short8*)(Vt + (size_t)(16 * ni + c) * 2048 + ktn + g * 8);

    // S = Q K^T : S[row=(g*4+r)+16mi][col=c+16ni]
    f32x4 sA[2][2] = {};
#pragma unroll
    for (int mi = 0; mi < 2; ++mi)
#pragma unroll
      for (int ni = 0; ni < 2; ++ni)
#pragma unroll
        for (int cs = 0; cs < 2; ++cs)
          sA[mi][ni] = __builtin_amdgcn_mfma_f32_16x16x32_bf16(qa[mi][cs], kf[ni][cs],
                                                               sA[mi][ni], 0, 0, 0);

    // mask + scale
    float sv[2][2][4];
#pragma unroll
    for (int mi = 0; mi < 2; ++mi)
#pragma unroll
      for (int ni = 0; ni < 2; ++ni)
#pragma unroll
        for (int r = 0; r < 4; ++r) {
          int q = qw0 + 16 * mi + 4 * g + r;
          int k = kt + 16 * ni + c;
          sv[mi][ni][r] = ((unsigned)(q - k) <= 256u) ? sA[mi][ni][r] * 0.125f : -3.0e38f;
        }

    // online softmax per q-row (mi, r); k spread over 16 lanes x 2 regs
#pragma unroll
    for (int mi = 0; mi < 2; ++mi) {
#pragma unroll
      for (int r = 0; r < 4; ++r) {
        float tm = fmaxf(sv[mi][0][r], sv[mi][1][r]);
        tm = fmaxf(tm, __shfl_xor(tm, 1));
        tm = fmaxf(tm, __shfl_xor(tm, 2));
        tm = fmaxf(tm, __shfl_xor(tm, 4));
        tm = fmaxf(tm, __shfl_xor(tm, 8));
        float mnew = fmaxf(mrow[mi][r], tm);
        float sc = __expf(mrow[mi][r] - mnew);
        mrow[mi][r] = mnew;
        float p0 = __expf(sv[mi][0][r] - mnew);
        float p1 = __expf(sv[mi][1][r] - mnew);
        float ps = p0 + p1;
        ps += __shfl_xor(ps, 1);
        ps += __shfl_xor(ps, 2);
        ps += __shfl_xor(ps, 4);
        ps += __shfl_xor(ps, 8);
        lsum[mi][r] = lsum[mi][r] * sc + ps;
#pragma unroll
        for (int ni = 0; ni < 4; ++ni)
          o[mi][ni][r] *= sc;
        // P[qloc][k] -> LDS, byte ^= ((qloc&12)<<2) to spread g-groups
        int qloc = 16 * mi + 4 * g + r;
        int xr = (qloc & 12) << 2;
        *(unsigned short*)(Pb + ((qloc * 64 + c * 2) ^ xr)) = f2bf(p0);
        *(unsigned short*)(Pb + ((qloc * 64 + 32 + c * 2) ^ xr)) = f2bf(p1);
      }
    }

    // P A-frags (row q=c, k=g*8+e) and PV MFMAs vs V^T B-frags
#pragma unroll
    for (int mi = 0; mi < 2; ++mi) {
      int qloc = 16 * mi + c;
      short8 pa = *(const short8*)(Pb + ((qloc * 64 + g * 16) ^ ((qloc & 12) << 2)));
#pragma unroll
      for (int ni = 0; ni < 4; ++ni)
        o[mi][ni] = __builtin_amdgcn_mfma_f32_16x16x32_bf16(pa, vf[ni], o[mi][ni], 0, 0, 0);
    }

#pragma unroll
    for (int ni = 0; ni < 2; ++ni)
#pragma unroll
      for (int cs = 0; cs < 2; ++cs)
        kf[ni][cs] = kfn[ni][cs];
#pragma unroll
    for (int ni = 0; ni < 4; ++ni)
      vf[ni] = vfn[ni];
  }

  // epilogue: normalize, write AO[token][h*64+d] bf16
#pragma unroll
  for (int mi = 0; mi < 2; ++mi)
#pragma unroll
    for (int r = 0; r < 4; ++r) {
      float inv = 1.f / lsum[mi][r];
      int q = qw0 + 16 * mi + 4 * g + r;
      unsigned short* row = AO + (size_t)(b * 2048 + q) * 1024 + h * 64 + c;
#pragma unroll
      for (int ni = 0; ni < 4; ++ni)
        row[16 * ni] = f2bf(o[mi][ni][r] * inv);
    }
}

extern "C" void kernel_launch(void* const* d_in, const int* in_sizes, int n_in,
                              void* d_out, int out_size, void* d_ws, size_t ws_size,
                              hipStream_t stream) {
  const float* X  = (const float*)d_in[0];
  const float* wq = (const float*)d_in[1];
  const float* bq = (const float*)d_in[2];
  const float* wk = (const float*)d_in[3];
  const float* bk = (const float*)d_in[4];
  const float* wv = (const float*)d_in[5];
  const float* bv = (const float*)d_in[6];
  const float* wo = (const float*)d_in[7];
  const float* bo = (const float*)d_in[8];
  float* out = (float*)d_out;

  // workspace (ushort elems): Xb[4194304] | Wb[4x1048576] | QKV[3x4194304] | AO[4194304]
  unsigned short* Xb  = (unsigned short*)d_ws;
  unsigned short* Wb  = Xb + 4194304;
  unsigned short* QKV = Wb + 4194304;
  unsigned short* AO  = QKV + 12582912;

  cvt4<<<dim3(4096), dim3(256), 0, stream>>>(X, Xb);
  cvt_w<<<dim3(1024, 1, 4), dim3(256), 0, stream>>>(wq, wk, wv, wo, Wb);
  gemm_bt<0><<<dim3(8, 32, 3), dim3(256), 0, stream>>>(Xb, Wb, bq, bk, bv, QKV, nullptr);
  attn_mfma<<<dim3(16, 16, 2), dim3(256), 0, stream>>>(QKV, AO);
  gemm_bt<1><<<dim3(8, 32, 1), dim3(256), 0, stream>>>(AO, Wb + 3 * 1048576, bo, bo, bo, nullptr, out);
}